// Round 5
// baseline (4117.158 us; speedup 1.0000x reference)
//
#include <hip/hip_runtime.h>

typedef unsigned short u16;
typedef __bf16 bf16x8 __attribute__((ext_vector_type(8)));
typedef float f32x4 __attribute__((ext_vector_type(4)));

#define AS1 __attribute__((address_space(1)))
#define AS3 __attribute__((address_space(3)))

// B=256, A=5, T=64, NIN=4, NHID=256, L=2, H=1280, 4H=5120, steps=63

__device__ __forceinline__ u16 f2bf(float f) {
    union { float f; unsigned int u; } v; v.f = f;
    unsigned int r = v.u + 0x7fffu + ((v.u >> 16) & 1u);
    return (u16)(r >> 16);
}

__device__ __forceinline__ void ld_lds16(const u16* g, u16* l) {
    __builtin_amdgcn_global_load_lds((AS1 unsigned int*)(unsigned long long)(const void*)g,
                                     (AS3 unsigned int*)l, 16, 0, 0);
}

__device__ __forceinline__ float sigm(float x) { return 1.f / (1.f + __expf(-x)); }
__device__ __forceinline__ float tanh_f(float x) { return 1.f - 2.f / (__expf(2.f * x) + 1.f); }

// ---------------------------------------------------------------------------
// Weight-prep kernels
// ---------------------------------------------------------------------------
__global__ __launch_bounds__(256) void cvt_kernel(const float* __restrict__ src,
                                                  u16* __restrict__ dst, int n) {
    int i = (blockIdx.x * 256 + threadIdx.x) * 4;
    if (i >= n) return;
    float4 v = *(const float4*)(src + i);
    ushort4 o;
    o.x = f2bf(v.x); o.y = f2bf(v.y); o.z = f2bf(v.z); o.w = f2bf(v.w);
    *(ushort4*)(dst + i) = o;
}

// wcat[l][j*4+g][k]: k<1280 -> w_ih[l][g*1280+j][k], else w_hh[..][k-1280]
__global__ __launch_bounds__(256) void cvt_wcat(const float* __restrict__ wih,
                                                const float* __restrict__ whh,
                                                u16* __restrict__ dst) {
    long long idx = ((long long)blockIdx.x * 256 + threadIdx.x) * 4;
    int k = (int)(idx % 2560);
    long long rr = idx / 2560;
    int l = (int)(rr / 5120), r = (int)(rr % 5120);
    int j = r >> 2, g = r & 3;
    long long srow = (long long)l * 5120 + g * 1280 + j;
    const float* s = (k < 1280) ? (wih + srow * 1280 + k) : (whh + srow * 1280 + (k - 1280));
    float4 v = *(const float4*)s;
    ushort4 o;
    o.x = f2bf(v.x); o.y = f2bf(v.y); o.z = f2bf(v.z); o.w = f2bf(v.w);
    *(ushort4*)(dst + idx) = o;
}

// w12p[kk][j] = pack(bf(w1_2[j][2kk]), bf(w1_2[j][2kk+1]))
__global__ __launch_bounds__(256) void cvt_w12p(const float* __restrict__ w,
                                                unsigned int* __restrict__ dst) {
    int idx = blockIdx.x * 256 + threadIdx.x;  // 32768
    int kk = idx >> 8, j = idx & 255;
    float f0 = w[j * 256 + 2 * kk], f1 = w[j * 256 + 2 * kk + 1];
    dst[idx] = (unsigned)f2bf(f0) | ((unsigned)f2bf(f1) << 16);
}

// ---------------------------------------------------------------------------
// core64: 64x128 tile, K=1280 (20 iters), BK=64, triple-buffered prefetch.
// ---------------------------------------------------------------------------
__device__ __forceinline__ void core64(
    const u16* A, int lda, const u16* Bw, int ldb,
    int m0, int n0, u16* As, u16* Bs, f32x4 (&acc)[2][4]) {
    const int nIter = 20;
    int tid = threadIdx.x;
    int w = tid >> 6, l = tid & 63;
    int r8 = l >> 3, g8 = (l & 7) ^ r8;
    const u16* aP = A + (size_t)(m0 + w * 8 + r8) * lda + g8 * 8;
    const u16* bP = Bw + (size_t)(n0 + w * 8 + r8) * ldb + g8 * 8;
    u16* aD = As + w * 512;
    u16* bD = Bs + w * 512;

#define ISSUE64(it)                                            \
    {                                                          \
        int bsel = (it) % 3;                                   \
        const u16* ap = aP + (it) * 64;                        \
        const u16* bp = bP + (it) * 64;                        \
        u16* ad = aD + bsel * 4096;                            \
        u16* bd = bD + bsel * 8192;                            \
        ld_lds16(ap, ad);                                      \
        ld_lds16(ap + (size_t)32 * lda, ad + 2048);            \
        ld_lds16(bp, bd);                                      \
        ld_lds16(bp + (size_t)32 * ldb, bd + 2048);            \
        ld_lds16(bp + (size_t)64 * ldb, bd + 4096);            \
        ld_lds16(bp + (size_t)96 * ldb, bd + 6144);            \
    }

    ISSUE64(0);
    ISSUE64(1);
    int wm = w >> 1, wn = w & 1, q = l >> 4, m16 = l & 15;
    for (int it = 0; it < nIter; ++it) {
        if (it + 2 < nIter) ISSUE64(it + 2);
        int ahead = nIter - 1 - it; if (ahead > 2) ahead = 2;
        if (ahead == 2) asm volatile("s_waitcnt vmcnt(12)" ::: "memory");
        else if (ahead == 1) asm volatile("s_waitcnt vmcnt(6)" ::: "memory");
        else asm volatile("s_waitcnt vmcnt(0)" ::: "memory");
        asm volatile("s_barrier" ::: "memory");
        const u16* as = As + (it % 3) * 4096;
        const u16* bs = Bs + (it % 3) * 8192;
#pragma unroll
        for (int ks = 0; ks < 2; ks++) {
            bf16x8 af[2], bfr[4];
            int gsw = (ks * 4 + q) ^ (m16 & 7);
#pragma unroll
            for (int i = 0; i < 2; i++) {
                int m = wm * 32 + i * 16 + m16;
                af[i] = *(const bf16x8*)&as[m * 64 + gsw * 8];
            }
#pragma unroll
            for (int j = 0; j < 4; j++) {
                int n = wn * 64 + j * 16 + m16;
                bfr[j] = *(const bf16x8*)&bs[n * 64 + gsw * 8];
            }
#pragma unroll
            for (int i = 0; i < 2; i++)
#pragma unroll
                for (int j = 0; j < 4; j++)
                    acc[i][j] = __builtin_amdgcn_mfma_f32_16x16x32_bf16(af[i], bfr[j], acc[i][j], 0, 0, 0);
        }
        asm volatile("s_barrier" ::: "memory");
    }
#undef ISSUE64
}

// ---------------------------------------------------------------------------
// core128: 128x128 tile, K=1280 (20 iters), wave-tile 64x64, triple-buffered.
// ---------------------------------------------------------------------------
__device__ __forceinline__ void core128(
    const u16* A, int lda, const u16* Bw, int ldb,
    int m0, int n0, u16* As, u16* Bs, f32x4 (&acc)[4][4]) {
    const int nIter = 20;
    int tid = threadIdx.x;
    int w = tid >> 6, l = tid & 63;
    int r8 = l >> 3, g8 = (l & 7) ^ r8;
    const u16* aP = A + (size_t)(m0 + w * 32 + r8) * lda + g8 * 8;
    const u16* bP = Bw + (size_t)(n0 + w * 32 + r8) * ldb + g8 * 8;
    u16* aD = As + w * 2048;
    u16* bD = Bs + w * 2048;

#define ISSUE128(it)                                           \
    {                                                          \
        int bsel = (it) % 3;                                   \
        const u16* ap = aP + (it) * 64;                        \
        const u16* bp = bP + (it) * 64;                        \
        u16* ad = aD + bsel * 8192;                            \
        u16* bd = bD + bsel * 8192;                            \
        ld_lds16(ap, ad);                                      \
        ld_lds16(ap + (size_t)8 * lda, ad + 512);              \
        ld_lds16(ap + (size_t)16 * lda, ad + 1024);            \
        ld_lds16(ap + (size_t)24 * lda, ad + 1536);            \
        ld_lds16(bp, bd);                                      \
        ld_lds16(bp + (size_t)8 * ldb, bd + 512);              \
        ld_lds16(bp + (size_t)16 * ldb, bd + 1024);            \
        ld_lds16(bp + (size_t)24 * ldb, bd + 1536);            \
    }

    ISSUE128(0);
    ISSUE128(1);
    int wm = w >> 1, wn = w & 1, q = l >> 4, m16 = l & 15;
    for (int it = 0; it < nIter; ++it) {
        if (it + 2 < nIter) ISSUE128(it + 2);
        int ahead = nIter - 1 - it; if (ahead > 2) ahead = 2;
        if (ahead == 2) asm volatile("s_waitcnt vmcnt(16)" ::: "memory");
        else if (ahead == 1) asm volatile("s_waitcnt vmcnt(8)" ::: "memory");
        else asm volatile("s_waitcnt vmcnt(0)" ::: "memory");
        asm volatile("s_barrier" ::: "memory");
        const u16* as = As + (it % 3) * 8192;
        const u16* bs = Bs + (it % 3) * 8192;
#pragma unroll
        for (int ks = 0; ks < 2; ks++) {
            bf16x8 af[4], bfr[4];
            int gsw = (ks * 4 + q) ^ (m16 & 7);
#pragma unroll
            for (int i = 0; i < 4; i++) {
                int m = wm * 64 + i * 16 + m16;
                af[i] = *(const bf16x8*)&as[m * 64 + gsw * 8];
            }
#pragma unroll
            for (int j = 0; j < 4; j++) {
                int n = wn * 64 + j * 16 + m16;
                bfr[j] = *(const bf16x8*)&bs[n * 64 + gsw * 8];
            }
#pragma unroll
            for (int i = 0; i < 4; i++)
#pragma unroll
                for (int j = 0; j < 4; j++)
                    acc[i][j] = __builtin_amdgcn_mfma_f32_16x16x32_bf16(af[i], bfr[j], acc[i][j], 0, 0, 0);
        }
        asm volatile("s_barrier" ::: "memory");
    }
#undef ISSUE128
}

// ---------------------------------------------------------------------------
// gates + fused cell body (64x128 tile over [256]x[5120] gates, K=1280)
// ---------------------------------------------------------------------------
__device__ __forceinline__ void gates_body(
    int blk, const u16* A, const u16* Bw, const float* ghh,
    const float* bih, const float* bhh, float* cst, u16* hout, char* smem) {
    u16* As = (u16*)smem;
    u16* Bs = (u16*)(smem + 24576);
    float (*cb)[132] = (float(*)[132])smem;   // overlay after core

    int nb = blk % 40, mb = blk / 40;
    int n0 = nb * 128, m0 = mb * 64;

    f32x4 acc[2][4];
#pragma unroll
    for (int i = 0; i < 2; i++)
#pragma unroll
        for (int j = 0; j < 4; j++) acc[i][j] = (f32x4){0.f, 0.f, 0.f, 0.f};

    core64(A, 1280, Bw, 2560, m0, n0, As, Bs, acc);

    int tid = threadIdx.x;
    int w = tid >> 6, l = tid & 63;
    int wm = w >> 1, wn = w & 1, q = l >> 4, m16 = l & 15;
#pragma unroll
    for (int i = 0; i < 2; i++)
#pragma unroll
        for (int j = 0; j < 4; j++)
#pragma unroll
            for (int r = 0; r < 4; r++) {
                int rl = wm * 32 + i * 16 + q * 4 + r;
                int cl = wn * 64 + j * 16 + m16;
                cb[rl][cl] = acc[i][j][r] + ghh[(size_t)(m0 + rl) * 5120 + n0 + cl];
            }
    __syncthreads();

    int jt = tid & 31, bt0 = tid >> 5;
    int jg = (n0 >> 2) + jt;
    float bI = bih[jg] + bhh[jg];
    float bF = bih[1280 + jg] + bhh[1280 + jg];
    float bG = bih[2560 + jg] + bhh[2560 + jg];
    float bO = bih[3840 + jg] + bhh[3840 + jg];
#pragma unroll
    for (int p = 0; p < 8; p++) {
        int bt = bt0 + p * 8;
        float4 g4 = *(const float4*)&cb[bt][jt * 4];   // i,f,g,o
        int b = m0 + bt;
        float cv = cst[b * 1280 + jg];
        float cn = sigm(g4.y + bF) * cv + sigm(g4.x + bI) * tanh_f(g4.z + bG);
        cst[b * 1280 + jg] = cn;
        hout[(size_t)b * 1280 + jg] = f2bf(sigm(g4.w + bO) * tanh_f(cn));
    }
}

// KA: 160 blocks, gates0 = x @ w_ih0^T + ghh0 -> h0, c0
__global__ __launch_bounds__(256) void k_gates(
    const u16* __restrict__ A, const u16* __restrict__ Bw,
    const float* __restrict__ ghh,
    const float* __restrict__ bih, const float* __restrict__ bhh,
    float* __restrict__ cst, u16* __restrict__ hout) {
    __shared__ __align__(16) char smem[73728];
    gates_body(blockIdx.x, A, Bw, ghh, bih, bhh, cst, hout, smem);
}

// KB: 240 blocks. blk<160: gates1 = h0 @ w_ih1^T + ghh1 -> h1, c1.
//                 blk>=160: ghh0' = h0 @ w_hh0^T (128x128 tiles).
__global__ __launch_bounds__(256) void k_gatesB(
    const u16* __restrict__ h0, const u16* __restrict__ Bw,
    const float* __restrict__ ghh_in,
    const float* __restrict__ bih, const float* __restrict__ bhh,
    float* __restrict__ cst, u16* __restrict__ hout,
    const u16* __restrict__ Bhh, float* __restrict__ ghh_out) {
    __shared__ __align__(16) char smem[98304];
    int blk = blockIdx.x;
    if (blk < 160) {
        gates_body(blk, h0, Bw, ghh_in, bih, bhh, cst, hout, smem);
        return;
    }
    int task = blk - 160;
    int mb = task / 40, nb = task % 40;
    int m0 = mb * 128, n0 = nb * 128;
    u16* As = (u16*)smem;
    u16* Bs = (u16*)(smem + 49152);
    f32x4 acc[4][4];
#pragma unroll
    for (int i = 0; i < 4; i++)
#pragma unroll
        for (int j = 0; j < 4; j++) acc[i][j] = (f32x4){0.f, 0.f, 0.f, 0.f};
    core128(h0, 1280, Bhh, 2560, m0, n0, As, Bs, acc);
    int tid = threadIdx.x;
    int w = tid >> 6, l = tid & 63;
    int wm = w >> 1, wn = w & 1, q = l >> 4, m16 = l & 15;
#pragma unroll
    for (int i = 0; i < 4; i++) {
        int row = m0 + wm * 64 + i * 16 + q * 4;
#pragma unroll
        for (int j = 0; j < 4; j++) {
            int col = n0 + wn * 64 + j * 16 + m16;
#pragma unroll
            for (int r = 0; r < 4; r++)
                ghh_out[(size_t)(row + r) * 5120 + col] = acc[i][j][r];
        }
    }
}

// ---------------------------------------------------------------------------
// KC': 208 blocks.
//  blk<40   : y-tile = relu(h1@w21^T+b21) in LDS -> head partial atomicAdd ->
//             release counter -> join -> finalize+MLP (2 samples).
//  40..127  : join -> finalize+MLP (2 samples).
//  128..207 : ghh1' = h1 @ w_hh1^T (128x128 tiles).
// All cross-block data inside this kernel flows through coherent atomics only.
// ---------------------------------------------------------------------------
__global__ __launch_bounds__(256) void k_c2(
    const u16* __restrict__ h1, const u16* __restrict__ w21,
    const float* __restrict__ b21, const float* __restrict__ w22,
    const float* __restrict__ b22, const u16* __restrict__ wcat,
    const float* __restrict__ inputs, const int* __restrict__ ps,
    const float* __restrict__ w11, const float* __restrict__ b11,
    const unsigned int* __restrict__ w12p, const float* __restrict__ b12,
    float* __restrict__ ghh1, float* __restrict__ out_acc,
    unsigned int* __restrict__ cnt, float* __restrict__ ins_buf,
    u16* __restrict__ xbf, float* __restrict__ out,
    int t, unsigned int target) {
    __shared__ __align__(16) char smem[98304];
    int blk = blockIdx.x, tid = threadIdx.x;
    int w = tid >> 6, l = tid & 63;

    if (blk >= 128) {  // ghh1' path
        int task = blk - 128;
        int mb = task / 40, nb = task % 40;
        int m0 = mb * 128, n0 = nb * 128;
        u16* As = (u16*)smem;
        u16* Bs = (u16*)(smem + 49152);
        f32x4 acc[4][4];
#pragma unroll
        for (int i = 0; i < 4; i++)
#pragma unroll
            for (int j = 0; j < 4; j++) acc[i][j] = (f32x4){0.f, 0.f, 0.f, 0.f};
        core128(h1, 1280, wcat + 13107200 + 1280, 2560, m0, n0, As, Bs, acc);
        int wm = w >> 1, wn = w & 1, q = l >> 4, m16 = l & 15;
#pragma unroll
        for (int i = 0; i < 4; i++) {
            int row = m0 + wm * 64 + i * 16 + q * 4;
#pragma unroll
            for (int j = 0; j < 4; j++) {
                int col = n0 + wn * 64 + j * 16 + m16;
#pragma unroll
                for (int r = 0; r < 4; r++)
                    ghh1[(size_t)(row + r) * 5120 + col] = acc[i][j][r];
            }
        }
        return;
    }

    if (blk < 40) {  // y-partial producer
        u16* As = (u16*)smem;
        u16* Bs = (u16*)(smem + 24576);
        int nb = blk % 10, mb = blk / 10;
        int n0 = nb * 128, m0 = mb * 64;
        f32x4 acc[2][4];
#pragma unroll
        for (int i = 0; i < 2; i++)
#pragma unroll
            for (int j = 0; j < 4; j++) acc[i][j] = (f32x4){0.f, 0.f, 0.f, 0.f};
        core64(h1, 1280, w21, 1280, m0, n0, As, Bs, acc);

        float* ylds = (float*)smem;  // [64][132], overlays As/Bs (core done)
        int wm = w >> 1, wn = w & 1, q = l >> 4, m16 = l & 15;
#pragma unroll
        for (int i = 0; i < 2; i++)
#pragma unroll
            for (int j = 0; j < 4; j++)
#pragma unroll
                for (int r = 0; r < 4; r++) {
                    int rl = wm * 32 + i * 16 + q * 4 + r;
                    int cl = wn * 64 + j * 16 + m16;
                    ylds[rl * 132 + cl] = fmaxf(acc[i][j][r] + b21[n0 + cl], 0.f);
                }
        __syncthreads();

        // head partial: wave w covers local k in [w*32, w*32+32)
        float a20[20];
#pragma unroll
        for (int j = 0; j < 20; j++) a20[j] = 0.f;
        int row = l;
#pragma unroll
        for (int kq = 0; kq < 8; kq++) {
            int kl = w * 32 + kq * 4;
            f32x4 y4 = *(const f32x4*)&ylds[row * 132 + kl];
#pragma unroll
            for (int j = 0; j < 20; j++) {
                float4 wv = *(const float4*)&w22[j * 1280 + n0 + kl];
                a20[j] += y4[0] * wv.x + y4[1] * wv.y + y4[2] * wv.z + y4[3] * wv.w;
            }
        }
        float* red = (float*)(smem + 33792);  // [4][64][21]
#pragma unroll
        for (int j = 0; j < 20; j++) red[(w * 64 + row) * 21 + j] = a20[j];
        __syncthreads();
#pragma unroll
        for (int base = 0; base < 1280; base += 256) {
            int idx = base + tid;
            int r2 = idx / 20, j2 = idx % 20;
            float s = red[r2 * 21 + j2] + red[(64 + r2) * 21 + j2]
                    + red[(128 + r2) * 21 + j2] + red[(192 + r2) * 21 + j2];
            atomicAdd(&out_acc[(m0 + r2) * 20 + j2], s);
        }
        __syncthreads();
        if (tid == 0)
            __hip_atomic_fetch_add(cnt, 1u, __ATOMIC_RELEASE, __HIP_MEMORY_SCOPE_AGENT);
    }

    // ---- join (blocks 0..127) ----
    if (tid == 0) {
        while (__hip_atomic_load(cnt, __ATOMIC_RELAXED, __HIP_MEMORY_SCOPE_AGENT) < target)
            __builtin_amdgcn_s_sleep(2);
    }
    __syncthreads();

    // finalize head + teacher select + MLP1 + MLP2 for samples 2*blk, 2*blk+1
    float* act1 = (float*)smem;            // [2][5][256]
    float* ins_s = (float*)(smem + 10240); // [2][20]
    int psv = ps[0];
#pragma unroll
    for (int s = 0; s < 2; s++) {
        int b = blk * 2 + s;
        if (tid < 20) {
            float v = __hip_atomic_load(&out_acc[b * 20 + tid], __ATOMIC_RELAXED,
                                        __HIP_MEMORY_SCOPE_AGENT)
                      + b22[tid] + ins_buf[b * 20 + tid];
            int a = tid >> 2, n = tid & 3;
            out[(((size_t)b * 5 + a) * 63 + t) * 4 + n] = v;
            __hip_atomic_store(&out_acc[b * 20 + tid], 0.f, __ATOMIC_RELAXED,
                               __HIP_MEMORY_SCOPE_AGENT);
            float nx = (((t + 1) % psv) == 0)
                           ? inputs[(((size_t)b * 5 + a) * 64 + (t + 1)) * 4 + n] : v;
            ins_s[s * 20 + tid] = nx;
            ins_buf[b * 20 + tid] = nx;
        }
    }
    __syncthreads();

    int j = tid;
    float4 wv = *(const float4*)(w11 + j * 4);
    float bb = b11[j];
#pragma unroll
    for (int s = 0; s < 2; s++)
#pragma unroll
        for (int g = 0; g < 5; g++) {
            float v = fmaf(wv.x, ins_s[s * 20 + g * 4],
                      fmaf(wv.y, ins_s[s * 20 + g * 4 + 1],
                      fmaf(wv.z, ins_s[s * 20 + g * 4 + 2],
                      fmaf(wv.w, ins_s[s * 20 + g * 4 + 3], bb))));
            act1[(s * 5 + g) * 256 + j] = fmaxf(v, 0.f);
        }
    __syncthreads();

    float bb2 = b12[j];
    float acc2[2][5];
#pragma unroll
    for (int s = 0; s < 2; s++)
#pragma unroll
        for (int g = 0; g < 5; g++) acc2[s][g] = bb2;
    for (int kk2 = 0; kk2 < 64; kk2++) {
        unsigned p0 = w12p[(2 * kk2) * 256 + j];
        unsigned p1 = w12p[(2 * kk2 + 1) * 256 + j];
        union { unsigned u; float f; } l0, h0v, l1, h1v;
        l0.u = p0 << 16; h0v.u = p0 & 0xffff0000u;
        l1.u = p1 << 16; h1v.u = p1 & 0xffff0000u;
#pragma unroll
        for (int s = 0; s < 2; s++)
#pragma unroll
            for (int g = 0; g < 5; g++) {
                f32x4 a4 = *(const f32x4*)&act1[(s * 5 + g) * 256 + kk2 * 4];
                acc2[s][g] = fmaf(l0.f, a4[0], fmaf(h0v.f, a4[1],
                             fmaf(l1.f, a4[2], fmaf(h1v.f, a4[3], acc2[s][g]))));
            }
    }
#pragma unroll
    for (int s = 0; s < 2; s++)
#pragma unroll
        for (int g = 0; g < 5; g++)
            xbf[(size_t)(blk * 2 + s) * 1280 + g * 256 + j] = f2bf(fmaxf(acc2[s][g], 0.f));
}

// ---------------------------------------------------------------------------
// k_init: ins(0) (teacher) + MLP1 + MLP2 -> x(0), 256 blocks (1 sample each)
// ---------------------------------------------------------------------------
__global__ __launch_bounds__(256) void k_init(
    const float* __restrict__ inputs, const float* __restrict__ w11,
    const float* __restrict__ b11, const unsigned int* __restrict__ w12p,
    const float* __restrict__ b12, float* __restrict__ ins_buf,
    u16* __restrict__ xbf) {
    __shared__ float act1[5 * 256];
    __shared__ float ins_s[20];
    int b = blockIdx.x, tid = threadIdx.x;
    if (tid < 20) {
        int a = tid >> 2, n = tid & 3;
        float nx = inputs[(((size_t)b * 5 + a) * 64) * 4 + n];
        ins_s[tid] = nx;
        ins_buf[b * 20 + tid] = nx;
    }
    __syncthreads();
    int j = tid;
    float4 wv = *(const float4*)(w11 + j * 4);
    float bb = b11[j];
#pragma unroll
    for (int g = 0; g < 5; g++) {
        float v = fmaf(wv.x, ins_s[g * 4],
                  fmaf(wv.y, ins_s[g * 4 + 1],
                  fmaf(wv.z, ins_s[g * 4 + 2],
                  fmaf(wv.w, ins_s[g * 4 + 3], bb))));
        act1[g * 256 + j] = fmaxf(v, 0.f);
    }
    __syncthreads();
    float acc2[5];
    float bb2 = b12[j];
#pragma unroll
    for (int g = 0; g < 5; g++) acc2[g] = bb2;
    for (int kk2 = 0; kk2 < 64; kk2++) {
        unsigned p0 = w12p[(2 * kk2) * 256 + j];
        unsigned p1 = w12p[(2 * kk2 + 1) * 256 + j];
        union { unsigned u; float f; } l0, h0v, l1, h1v;
        l0.u = p0 << 16; h0v.u = p0 & 0xffff0000u;
        l1.u = p1 << 16; h1v.u = p1 & 0xffff0000u;
#pragma unroll
        for (int g = 0; g < 5; g++) {
            f32x4 a4 = *(const f32x4*)&act1[g * 256 + kk2 * 4];
            acc2[g] = fmaf(l0.f, a4[0], fmaf(h0v.f, a4[1],
                       fmaf(l1.f, a4[2], fmaf(h1v.f, a4[3], acc2[g]))));
        }
    }
#pragma unroll
    for (int g = 0; g < 5; g++)
        xbf[(size_t)b * 1280 + g * 256 + j] = f2bf(fmaxf(acc2[g], 0.f));
}

// ---------------------------------------------------------------------------
extern "C" void kernel_launch(void* const* d_in, const int* in_sizes, int n_in,
                              void* d_out, int out_size, void* d_ws, size_t ws_size,
                              hipStream_t stream) {
    const float* inputs = (const float*)d_in[0];
    const float* w1_1 = (const float*)d_in[1];
    const float* b1_1 = (const float*)d_in[2];
    const float* w1_2 = (const float*)d_in[3];
    const float* b1_2 = (const float*)d_in[4];
    const float* w_ih = (const float*)d_in[5];
    const float* w_hh = (const float*)d_in[6];
    const float* b_ih = (const float*)d_in[7];
    const float* b_hh = (const float*)d_in[8];
    const float* w2_1 = (const float*)d_in[9];
    const float* b2_1 = (const float*)d_in[10];
    const float* w2_2 = (const float*)d_in[11];
    const float* b2_2 = (const float*)d_in[12];
    const int* ps = (const int*)d_in[13];
    float* out = (float*)d_out;

    char* ws = (char*)d_ws;
    size_t off = 0;
    auto alloc = [&](size_t bytes) -> void* {
        void* p = ws + off;
        off = (off + bytes + 255) & ~(size_t)255;
        return p;
    };
    u16* wcat = (u16*)alloc(26214400ull * 2);        // [2][5120][2560]
    u16* w21_bf = (u16*)alloc(1638400ull * 2);       // [1280][1280]
    unsigned int* w12p = (unsigned int*)alloc(32768ull * 4);
    u16* xbf = (u16*)alloc(327680ull * 2);           // [256][1280]
    u16* h0 = (u16*)alloc(327680ull * 2);            // [256][1280]
    u16* h1 = (u16*)alloc(327680ull * 2);            // [256][1280]
    float* c0 = (float*)alloc(327680ull * 4);        // [256][1280]
    float* c1 = (float*)alloc(327680ull * 4);
    float* ghh0 = (float*)alloc(1310720ull * 4);     // [256][5120]
    float* ghh1 = (float*)alloc(1310720ull * 4);
    float* out_acc = (float*)alloc(5120ull * 4);     // [256][20]
    float* ins_b = (float*)alloc(5120ull * 4);       // [256][20]
    unsigned int* cnt = (unsigned int*)alloc(256);

    // weight prep + state init
    cvt_wcat<<<25600, 256, 0, stream>>>(w_ih, w_hh, wcat);
    cvt_kernel<<<1600, 256, 0, stream>>>(w2_1, w21_bf, 1638400);
    cvt_w12p<<<128, 256, 0, stream>>>(w1_2, w12p);
    hipMemsetAsync(c0, 0, 327680ull * 4, stream);
    hipMemsetAsync(c1, 0, 327680ull * 4, stream);
    hipMemsetAsync(ghh0, 0, 1310720ull * 4, stream);
    hipMemsetAsync(ghh1, 0, 1310720ull * 4, stream);
    hipMemsetAsync(out_acc, 0, 5120ull * 4, stream);
    hipMemsetAsync(cnt, 0, 256, stream);

    // t = -1: ins(0) select + MLP1 + MLP2 -> x(0)
    k_init<<<256, 256, 0, stream>>>(inputs, w1_1, b1_1, w12p, b1_2, ins_b, xbf);

    for (int t = 0; t < 63; t++) {
        // KA: gates0 = x @ w_ih0^T + ghh0 -> h0, c0
        k_gates<<<160, 256, 0, stream>>>(xbf, wcat, ghh0, b_ih, b_hh, c0, h0);
        // KB: gates1 = h0 @ w_ih1^T + ghh1 -> h1, c1  ||  ghh0' = h0 @ w_hh0^T
        k_gatesB<<<240, 256, 0, stream>>>(h0, wcat + 13107200, ghh1,
                                          b_ih + 5120, b_hh + 5120, c1, h1,
                                          wcat + 1280, ghh0);
        // KC': y+head partial -> join -> out/ins/MLP -> x(t+1)  ||  ghh1'
        k_c2<<<208, 256, 0, stream>>>(h1, w21_bf, b2_1, w2_2, b2_2, wcat,
                                      inputs, ps, w1_1, b1_1, w12p, b1_2,
                                      ghh1, out_acc, cnt, ins_b, xbf, out,
                                      t, 40u * (t + 1));
    }
}